// Round 5
// baseline (103.531 us; speedup 1.0000x reference)
//
#include <hip/hip_runtime.h>

#define H 1536
#define HK 8
#define HV 16
#define DK 64
#define DV 64
#define KEY_DIM 512
#define VALUE_DIM 1024
#define CONV_DIM 2048
#define NROWS1 (CONV_DIM + VALUE_DIM + HV + HV)   // 3104

__device__ __forceinline__ float wave_reduce_sum(float v) {
#pragma unroll
    for (int off = 32; off > 0; off >>= 1) v += __shfl_xor(v, off, 64);
    return v;
}
__device__ __forceinline__ float dot4(float4 a, float4 b) {
    return a.x * b.x + a.y * b.y + a.z * b.z + a.w * b.w;
}
__device__ __forceinline__ float conv_silu(int i,
        const float* __restrict__ ws, const float* __restrict__ conv_w,
        const float* __restrict__ conv_cache) {
    float raw = conv_cache[i * 3 + 0] * conv_w[i * 4 + 0]
              + conv_cache[i * 3 + 1] * conv_w[i * 4 + 1]
              + conv_cache[i * 3 + 2] * conv_w[i * 4 + 2]
              + ws[i]                 * conv_w[i * 4 + 3];
    return raw / (1.f + expf(-raw));               // silu
}

// K1: fused GEMV for W_qkv (2048), W_z (1024), W_a (16), W_b (16) vs x[1536].
// One 64-lane wave per row; 6 float4 loads per lane. (Round-0 proven kernel.)
__global__ __launch_bounds__(256) void gemv_in(
        const float* __restrict__ x,
        const float* __restrict__ Wqkv, const float* __restrict__ Wz,
        const float* __restrict__ Wa,   const float* __restrict__ Wb,
        float* __restrict__ ws) {
    const int wave = threadIdx.x >> 6;
    const int lane = threadIdx.x & 63;
    const int row  = blockIdx.x * 4 + wave;          // 776 blocks * 4 = 3104
    const float* wrow;
    if (row < CONV_DIM)                       wrow = Wqkv + (size_t)row * H;
    else if (row < CONV_DIM + VALUE_DIM)      wrow = Wz + (size_t)(row - CONV_DIM) * H;
    else if (row < CONV_DIM + VALUE_DIM + HV) wrow = Wa + (size_t)(row - CONV_DIM - VALUE_DIM) * H;
    else                                      wrow = Wb + (size_t)(row - CONV_DIM - VALUE_DIM - HV) * H;
    const float4* w4 = (const float4*)wrow;
    const float4* x4 = (const float4*)x;
    float acc = 0.f;
#pragma unroll
    for (int j = 0; j < 6; ++j) {                    // 1536/4/64 = 6
        float4 a = w4[lane + 64 * j];
        float4 b = x4[lane + 64 * j];
        acc += a.x * b.x + a.y * b.y + a.z * b.z + a.w * b.w;
    }
    acc = wave_reduce_sum(acc);
    if (lane == 0) ws[row] = acc;
}

// K2: each block REDUNDANTLY recomputes the full 16-head decode into LDS (no
// cross-block sync), then computes its own 16 rows of y = W_out @ og.
// T14 async-STAGE split: the wave's two W_out rows (8 float4/lane) are issued
// BEFORE the decode phase and pinned with asm so the 6.3 MB HBM stream hides
// under the ~2.5 us of decode VALU work; consumed after __syncthreads.
// Per-head math replicates the round-0 decode_core expressions and reduction
// order exactly, so y matches the proven kernel bitwise.
__global__ __launch_bounds__(512) void decode_y(
        const float* __restrict__ ws,                 // [qkv 2048 | z 1024 | a 16 | b 16]
        const float* __restrict__ conv_w,             // [2048,4]
        const float* __restrict__ conv_cache,         // [2048,3]
        const float* __restrict__ A_log, const float* __restrict__ dt_bias,
        const float* __restrict__ norm_w,             // [64]
        const float* __restrict__ state,              // [16,64,64]
        const float* __restrict__ Wout,               // [1536,1024]
        float* __restrict__ y) {                      // [1536]
    const int tid  = threadIdx.x;
    const int lane = tid & 63;
    const int wv   = tid >> 6;                        // 0..7 == head pair

    __shared__ float og_s[VALUE_DIM];                 // 4 KB

    // ---- T14 stage-issue: W_out rows for this wave, in flight across decode ----
    const int row0 = blockIdx.x * 16 + wv * 2;
    const float4* wr0 = (const float4*)(Wout + (size_t)row0 * VALUE_DIM);
    const float4* wr1 = (const float4*)(Wout + (size_t)(row0 + 1) * VALUE_DIM);
    float4 wo0[4], wo1[4];
#pragma unroll
    for (int j = 0; j < 4; ++j) wo0[j] = wr0[lane + 64 * j];
#pragma unroll
    for (int j = 0; j < 4; ++j) wo1[j] = wr1[lane + 64 * j];
    asm volatile("" :: "v"(wo0[0].x), "v"(wo0[1].x), "v"(wo0[2].x), "v"(wo0[3].x),
                       "v"(wo1[0].x), "v"(wo1[1].x), "v"(wo1[2].x), "v"(wo1[3].x));

    // ---- shared q/k for this pair (kv-group repeat: heads 2*wv, 2*wv+1) ----
    const int iq = wv * 64 + lane;                    // q row
    const int ik = KEY_DIM + wv * 64 + lane;          // k row
    float cq = conv_silu(iq, ws, conv_w, conv_cache);
    float ck = conv_silu(ik, ws, conv_w, conv_cache);
    float qn = cq * rsqrtf(wave_reduce_sum(cq * cq) + 1e-12f) * 0.125f;  // * Dk^-0.5
    float kn = ck * rsqrtf(wave_reduce_sum(ck * ck) + 1e-12f);
    float kq = wave_reduce_sum(kn * qn);              // k·q scalar

#pragma unroll
    for (int hh = 0; hh < 2; ++hh) {
        const int h = 2 * wv + hh;
        // v row + per-head scalars (computed redundantly by all lanes: same
        // scalar math on broadcast values -> deterministic).
        float cv = conv_silu(2 * KEY_DIM + h * 64 + lane, ws, conv_w, conv_cache);
        float aa = ws[CONV_DIM + VALUE_DIM + h] + dt_bias[h];
        float sp = (aa > 20.f) ? aa : log1pf(expf(aa));     // softplus
        float decay = expf(-expf(A_log[h]) * sp);
        float braw = ws[CONV_DIM + VALUE_DIM + HV + h];
        float beta = 1.f / (1.f + expf(-braw));

        // state contraction: 4 quarter accumulators, left-to-right combine
        // (replicates decode_core's red_r[tid]+red_r[64+tid]+... order).
        const float* st = state + (size_t)h * DK * DV;
        float pr[4] = {0.f, 0.f, 0.f, 0.f};
        float po[4] = {0.f, 0.f, 0.f, 0.f};
#pragma unroll
        for (int qq = 0; qq < 4; ++qq) {
#pragma unroll
            for (int kk = 0; kk < 16; ++kk) {
                const int kidx = qq * 16 + kk;
                float s  = st[kidx * 64 + lane];      // coalesced over v
                pr[qq] += s * __shfl(kn, kidx, 64);
                po[qq] += s * __shfl(qn, kidx, 64);
            }
        }
        float r = (((pr[0] + pr[1]) + pr[2]) + pr[3]) * decay;
        float o = (((po[0] + po[1]) + po[2]) + po[3]) * decay;
        float delta = (cv - r) * beta;
        float outv  = o + delta * kq;                 // new_state^T q, unmaterialized
        float ssum = wave_reduce_sum(outv * outv);
        float inv = rsqrtf(ssum * (1.f / 64.f) + 1e-6f);
        float zz  = ws[CONV_DIM + h * 64 + lane];
        float gate = zz / (1.f + expf(-zz));          // silu(z)
        og_s[h * 64 + lane] = norm_w[lane] * outv * inv * gate;
    }
    __syncthreads();

    // ---- y rows: 2 per wave from the preloaded registers; og from LDS ----
    const float4* og4 = (const float4*)og_s;
    const float4 b0 = og4[lane];
    const float4 b1 = og4[lane + 64];
    const float4 b2 = og4[lane + 128];
    const float4 b3 = og4[lane + 192];
    {
        float acc = 0.f;
        acc += dot4(wo0[0], b0);
        acc += dot4(wo0[1], b1);
        acc += dot4(wo0[2], b2);
        acc += dot4(wo0[3], b3);
        acc = wave_reduce_sum(acc);
        if (lane == 0) y[row0] = acc;
    }
    {
        float acc = 0.f;
        acc += dot4(wo1[0], b0);
        acc += dot4(wo1[1], b1);
        acc += dot4(wo1[2], b2);
        acc += dot4(wo1[3], b3);
        acc = wave_reduce_sum(acc);
        if (lane == 0) y[row0 + 1] = acc;
    }
}

extern "C" void kernel_launch(void* const* d_in, const int* in_sizes, int n_in,
                              void* d_out, int out_size, void* d_ws, size_t ws_size,
                              hipStream_t stream) {
    const float* x     = (const float*)d_in[0];
    const float* Wqkv  = (const float*)d_in[1];
    const float* Wz    = (const float*)d_in[2];
    const float* Wa    = (const float*)d_in[3];
    const float* Wb    = (const float*)d_in[4];
    const float* Wout  = (const float*)d_in[5];
    const float* convw = (const float*)d_in[6];
    const float* Alog  = (const float*)d_in[7];
    const float* dtb   = (const float*)d_in[8];
    const float* normw = (const float*)d_in[9];
    const float* state = (const float*)d_in[10];
    const float* cch   = (const float*)d_in[11];

    float* ws = (float*)d_ws;              // [0,3104): qkv|z|a|b
    float* y  = (float*)d_out;

    gemv_in<<<NROWS1 / 4, 256, 0, stream>>>(x, Wqkv, Wz, Wa, Wb, ws);
    decode_y<<<H / 16, 512, 0, stream>>>(ws, convw, cch, Alog, dtb, normw, state,
                                         Wout, y);
}